// Round 6
// baseline (2044.442 us; speedup 1.0000x reference)
//
#include <hip/hip_runtime.h>
#include <hip/hip_cooperative_groups.h>
#include <hip/hip_bf16.h>
#include <stdint.h>

namespace cg = cooperative_groups;

// ---------------------------------------------------------------------------
// E2E: LSTM1(8 steps) -> relu(linear)+BN1 -> concat -> xp2 -> LSTM2 tree(16)
//      -> BN2 -> out [1024,512] f32.
// R16: cell_gemm reverted to R12 (best measured: BN=256 2-phase drain,
// 78.5us/step). Tree fused into ONE cooperative kernel (cell0 + 15 levels,
// grid.sync between levels, h/c ping-pong in-kernel); runtime fallback to the
// 16-dispatch path if cooperative launch is unavailable.
// ---------------------------------------------------------------------------

typedef __bf16 bf16;
typedef __bf16 bf16x8 __attribute__((ext_vector_type(8)));
typedef float f32x4 __attribute__((ext_vector_type(4)));

#define HIDDEN 512

__device__ __forceinline__ float fast_sig(float x) { return 1.f / (1.f + __expf(-x)); }
__device__ __forceinline__ float fast_tanh(float x) {
  float e = __expf(2.f * x);
  return 1.f - 2.f / (e + 1.f);
}

__device__ __forceinline__ void async16(const bf16* g, bf16* l) {
  __builtin_amdgcn_global_load_lds(
      (const __attribute__((address_space(1))) void*)g,
      (__attribute__((address_space(3))) void*)l, 16, 0, 0);
}

// ---------------- merged prep: cvts + detect ----------------
__device__ __forceinline__ void cvt_one(const float* __restrict__ src,
                                        bf16* __restrict__ dst, size_t i) {
  float4 a = *(const float4*)(src + i);
  float4 b = *(const float4*)(src + i + 4);
  bf16x8 r;
  r[0] = (bf16)a.x; r[1] = (bf16)a.y; r[2] = (bf16)a.z; r[3] = (bf16)a.w;
  r[4] = (bf16)b.x; r[5] = (bf16)b.y; r[6] = (bf16)b.z; r[7] = (bf16)b.w;
  *(bf16x8*)(dst + i) = r;
}

__global__ void prep(const float* conds, bf16* conds_b,
                     const float* s0, bf16* d0, const float* s1, bf16* d1,
                     const float* s2, bf16* d2, const float* s3, bf16* d3,
                     const float* s4, bf16* d4, const float* s5, bf16* d5,
                     const float* s6, bf16* d6,
                     const int* map, int* flags) {
  int b = blockIdx.x;
  int tid = threadIdx.x;
  if (b < 2176) {
    int g = b * 256 + tid;
    const float* s; bf16* d; int off;
    if      (g < 65536)  { s = s0; d = d0; off = g; }
    else if (g < 131072) { s = s1; d = d1; off = g - 65536; }
    else if (g < 196608) { s = s2; d = d2; off = g - 131072; }
    else if (g < 327680) { s = s3; d = d3; off = g - 196608; }
    else if (g < 344064) { s = s4; d = d4; off = g - 327680; }
    else if (g < 425984) { s = s5; d = d5; off = g - 344064; }
    else if (g < 557056) { s = s6; d = d6; off = g - 425984; }
    else return;
    cvt_one(s, d, (size_t)off * 8);
  } else if (b == 2176) {
    __shared__ int any;
    if (tid == 0) any = 0;
    __syncthreads();
    int loc = 0;
    for (int i = tid; i < 16384; i += 256) loc |= map[2 * i + 1];
    if (loc) atomicOr(&any, 1);
    __syncthreads();
    if (tid == 0) flags[0] = (any == 0) ? 1 : 0;
  } else {
    size_t i = ((size_t)(b - 2177) * 256 + tid) * 8;
    cvt_one(conds, conds_b, i);
  }
}

// ---------------- LSTM1 fused GEMM + cell (BM=128 x BN=256, BK=64) ---------
// R12 variant (best measured). B-tile: 256 rows = 4 gates x 64 j-cols.
template <int MT, int KT0, int KT1>
__global__ __launch_bounds__(256, 2) void cell_gemm(
    const bf16* __restrict__ A0, int a0off, int a0s,
    const bf16* __restrict__ A1, int a1s,
    const bf16* __restrict__ B0, int b0s,
    const bf16* __restrict__ B1, int b1s,
    const float* __restrict__ bias0, const float* __restrict__ bias1,
    const float* __restrict__ c_prev,
    float* __restrict__ c_out,
    bf16* __restrict__ h_b16)
{
  constexpr int BM = MT * 32;
  __shared__ __align__(16) bf16 sA[BM * 64];
  __shared__ __align__(16) bf16 sB[256 * 64];
  const int tid = threadIdx.x;
  const int lane = tid & 63;
  const int quad = lane >> 4, cl = lane & 15;
  const int wave = tid >> 6;
  const int wr = wave >> 1, wc = wave & 1;
  const int bm0 = blockIdx.x * BM;
  const int j0 = blockIdx.y * 64;

  const bf16* ra[MT][2];
  const bf16* rb[8][2];
#pragma unroll
  for (int mi = 0; mi < MT; ++mi)
#pragma unroll
    for (int kh = 0; kh < 2; ++kh) {
      int row = wr * (MT * 16) + mi * 16 + cl;
      ra[mi][kh] = &sA[row * 64 + (((kh * 4 + quad) ^ (row & 7))) * 8];
    }
#pragma unroll
  for (int g = 0; g < 8; ++g)
#pragma unroll
    for (int kh = 0; kh < 2; ++kh) {
      int row = g * 32 + wc * 16 + cl;
      rb[g][kh] = &sB[row * 64 + (((kh * 4 + quad) ^ (row & 7))) * 8];
    }

  f32x4 acc[MT][8];
#pragma unroll
  for (int mi = 0; mi < MT; ++mi)
#pragma unroll
    for (int g = 0; g < 8; ++g) acc[mi][g] = f32x4{0.f, 0.f, 0.f, 0.f};

  const bf16* pa[MT];
  const bf16* pb[8];
#pragma unroll
  for (int ia = 0; ia < MT; ++ia) {
    int e = ia * 256 + tid, row = e >> 3, sl = e & 7;
    pa[ia] = A0 + (size_t)((bm0 + row) * a0s + a0off + (sl ^ (row & 7)) * 8);
  }
#pragma unroll
  for (int ib = 0; ib < 8; ++ib) {
    int e = ib * 256 + tid, row = e >> 3, sl = e & 7;
    int wrow = (row >> 6) * HIDDEN + j0 + (row & 63);
    pb[ib] = B0 + (size_t)(wrow * b0s + (sl ^ (row & 7)) * 8);
  }

  auto ktile = [&]() {
#pragma unroll
    for (int ia = 0; ia < MT; ++ia) {
      async16(pa[ia], sA + (ia * 256 + tid) * 8);
      pa[ia] += 64;
    }
#pragma unroll
    for (int ib = 0; ib < 8; ++ib) {
      async16(pb[ib], sB + (ib * 256 + tid) * 8);
      pb[ib] += 64;
    }
    __syncthreads();
#pragma unroll
    for (int kh = 0; kh < 2; ++kh) {
      bf16x8 af[MT], bfr[8];
#pragma unroll
      for (int mi = 0; mi < MT; ++mi) af[mi] = *(const bf16x8*)ra[mi][kh];
#pragma unroll
      for (int g = 0; g < 8; ++g) bfr[g] = *(const bf16x8*)rb[g][kh];
#pragma unroll
      for (int mi = 0; mi < MT; ++mi)
#pragma unroll
        for (int g = 0; g < 8; ++g)
          acc[mi][g] = __builtin_amdgcn_mfma_f32_16x16x32_bf16(af[mi], bfr[g], acc[mi][g], 0, 0, 0);
    }
    __syncthreads();
  };

  for (int kt = 0; kt < KT0; ++kt) ktile();
  if (KT1 > 0) {
#pragma unroll
    for (int ia = 0; ia < MT; ++ia) {
      int e = ia * 256 + tid, row = e >> 3, sl = e & 7;
      pa[ia] = A1 + (size_t)((bm0 + row) * a1s + (sl ^ (row & 7)) * 8);
    }
#pragma unroll
    for (int ib = 0; ib < 8; ++ib) {
      int e = ib * 256 + tid, row = e >> 3, sl = e & 7;
      int wrow = (row >> 6) * HIDDEN + j0 + (row & 63);
      pb[ib] = B1 + (size_t)(wrow * b1s + (sl ^ (row & 7)) * 8);
    }
    for (int kt = 0; kt < KT1; ++kt) ktile();
  }

#pragma unroll
  for (int h = 0; h < 2; ++h) {
    const int j = j0 + h * 32 + wc * 16 + cl;
    float bI = bias0[j] + bias1[j];
    float bF = bias0[HIDDEN + j] + bias1[HIDDEN + j];
    float bG = bias0[2 * HIDDEN + j] + bias1[2 * HIDDEN + j];
    float bO = bias0[3 * HIDDEN + j] + bias1[3 * HIDDEN + j];
#pragma unroll
    for (int mi = 0; mi < MT; ++mi) {
      int rb_ = bm0 + wr * (MT * 16) + mi * 16 + quad * 4;
#pragma unroll
      for (int r = 0; r < 4; ++r) {
        int row = rb_ + r;
        float iv = fast_sig(acc[mi][0 + h][r] + bI);
        float fv = fast_sig(acc[mi][2 + h][r] + bF);
        float gv = fast_tanh(acc[mi][4 + h][r] + bG);
        float ov = fast_sig(acc[mi][6 + h][r] + bO);
        float cp = c_prev ? c_prev[(size_t)row * HIDDEN + j] : 0.f;
        float cn = fv * cp + iv * gv;
        float hn = ov * fast_tanh(cn);
        c_out[(size_t)row * HIDDEN + j] = cn;
        h_b16[(size_t)row * HIDDEN + j] = (bf16)hn;
      }
    }
  }
}

// ---------------- shared device body: one tree level (gather+GEMM+cell) ----
__device__ __forceinline__ void tree_level_body(
    int bm0, int j0, int fl, int level,
    const int* __restrict__ map,
    const bf16* __restrict__ h_src, const float* __restrict__ c_src,
    const bf16* __restrict__ W, const float* __restrict__ bhh,
    const bf16* __restrict__ xp,
    float* __restrict__ c_out, bf16* __restrict__ h_out,
    float* __restrict__ h_f32,
    bf16* sA /*32*512*/, bf16* sB /*128*64*/)
{
  const int tid = threadIdx.x;
  const int lane = tid & 63;
  const int quad = lane >> 4, cl = lane & 15;
  const int wave = tid >> 6;
  const int wr = wave >> 1, wc = wave & 1;

  // ---- gather phase: sA[row][slot'] = bf16(0.5*(h[m0]+h[m1])) ----
  {
    int grow = tid >> 3;        // 0..31
    int w = tid & 7;
    int n = bm0 + grow;
    long mbase = (long)level * 2048 + n * 2;
    int m0, m1;
    if (fl) { m0 = map[mbase * 2]; m1 = map[mbase * 2 + 2]; }
    else    { m0 = map[mbase];     m1 = map[mbase + 1]; }
    const bf16* s0 = h_src + (size_t)(m0 ? m0 - 1 : 0) * HIDDEN;
    const bf16* s1 = h_src + (size_t)(m1 ? m1 - 1 : 0) * HIDDEN;
    float f0 = m0 ? 0.5f : 0.f;
    float f1 = m1 ? 0.5f : 0.f;
    int sw = grow & 7;
    bf16* drow = sA + grow * 512;
#pragma unroll
    for (int g = 0; g < 8; ++g) {
      int slot = g * 8 + w;
      bf16x8 a = *(const bf16x8*)(s0 + slot * 8);
      bf16x8 b = *(const bf16x8*)(s1 + slot * 8);
      bf16x8 r;
#pragma unroll
      for (int e = 0; e < 8; ++e)
        r[e] = (bf16)(f0 * (float)a[e] + f1 * (float)b[e]);
      *(bf16x8*)(drow + (g * 8 + (w ^ sw)) * 8) = r;
    }
  }

  const bf16* ra[2];
#pragma unroll
  for (int kh = 0; kh < 2; ++kh) {
    int row = wr * 16 + cl;
    ra[kh] = &sA[row * 512 + (((kh * 4 + quad) ^ (row & 7))) * 8];
  }
  const bf16* rb[4][2];
#pragma unroll
  for (int g = 0; g < 4; ++g)
#pragma unroll
    for (int kh = 0; kh < 2; ++kh) {
      int row = g * 32 + wc * 16 + cl;
      rb[g][kh] = &sB[row * 64 + (((kh * 4 + quad) ^ (row & 7))) * 8];
    }

  f32x4 acc[4];
#pragma unroll
  for (int g = 0; g < 4; ++g) acc[g] = f32x4{0.f, 0.f, 0.f, 0.f};

  const bf16* pb[4];
#pragma unroll
  for (int ib = 0; ib < 4; ++ib) {
    int e = ib * 256 + tid, row = e >> 3, sl = e & 7;
    int wrow = (row >> 5) * HIDDEN + j0 + (row & 31);
    pb[ib] = W + (size_t)(wrow * HIDDEN + (sl ^ (row & 7)) * 8);
  }

  for (int kt = 0; kt < 8; ++kt) {
#pragma unroll
    for (int ib = 0; ib < 4; ++ib) {
      async16(pb[ib], sB + (ib * 256 + tid) * 8);
      pb[ib] += 64;
    }
    __syncthreads();   // covers gather ds_writes on kt==0, B staging always
#pragma unroll
    for (int kh = 0; kh < 2; ++kh) {
      bf16x8 af = *(const bf16x8*)(ra[kh] + kt * 64);
#pragma unroll
      for (int g = 0; g < 4; ++g) {
        bf16x8 bfr = *(const bf16x8*)rb[g][kh];
        acc[g] = __builtin_amdgcn_mfma_f32_16x16x32_bf16(af, bfr, acc[g], 0, 0, 0);
      }
    }
    __syncthreads();
  }

  const int j = j0 + wc * 16 + cl;
  float bI = bhh[j], bF = bhh[HIDDEN + j];
  float bG = bhh[2 * HIDDEN + j], bO = bhh[3 * HIDDEN + j];
  int rb0 = bm0 + wr * 16 + quad * 4;
#pragma unroll
  for (int r = 0; r < 4; ++r) {
    int row = rb0 + r;
    long mbase = (long)level * 2048 + row * 2;
    int m0, m1;
    if (fl) { m0 = map[mbase * 2]; m1 = map[mbase * 2 + 2]; }
    else    { m0 = map[mbase];     m1 = map[mbase + 1]; }
    float c0 = m0 ? c_src[(size_t)(m0 - 1) * HIDDEN + j] : 0.f;
    float c1 = m1 ? c_src[(size_t)(m1 - 1) * HIDDEN + j] : 0.f;
    float cp = 0.5f * (c0 + c1);
    const bf16* xr = xp + (size_t)row * 2048;
    float gi = acc[0][r] + bI + (float)xr[j];
    float gf = acc[1][r] + bF + (float)xr[HIDDEN + j];
    float gg = acc[2][r] + bG + (float)xr[2 * HIDDEN + j];
    float go = acc[3][r] + bO + (float)xr[3 * HIDDEN + j];
    float cn = fast_sig(gf) * cp + fast_sig(gi) * fast_tanh(gg);
    float hn = fast_sig(go) * fast_tanh(cn);
    c_out[(size_t)row * HIDDEN + j] = cn;
    h_out[(size_t)row * HIDDEN + j] = (bf16)hn;
    if (h_f32) h_f32[(size_t)row * HIDDEN + j] = hn;
  }
}

// ---------------- fused cooperative tree: cell0 + 15 levels ----------------
__global__ __launch_bounds__(256, 2) void tree_fused(
    const int* __restrict__ map, const int* __restrict__ flags,
    const bf16* __restrict__ xp, const float* __restrict__ bhh,
    const bf16* __restrict__ W,
    bf16* __restrict__ h0, bf16* __restrict__ h1,
    float* __restrict__ c0, float* __restrict__ c1,
    float* __restrict__ h_f32)
{
  __shared__ __align__(16) bf16 sA[32 * 512];
  __shared__ __align__(16) bf16 sB[128 * 64];
  cg::grid_group grid = cg::this_grid();
  const int bm0 = (blockIdx.x & 31) * 32;
  const int j0 = (blockIdx.x >> 5) * 32;
  const int fl = flags[0];
  const size_t lvl_sz = (size_t)1024 * 2048;

  // ---- level 15: zero-state cell, 4 elems/thread ----
  {
    int gtid = blockIdx.x * 256 + threadIdx.x;
    const bf16* xp15 = xp + 15 * lvl_sz;
#pragma unroll
    for (int e = 0; e < 4; ++e) {
      int idx = gtid * 4 + e;
      int n = idx >> 9, j = idx & 511;
      float g[4];
#pragma unroll
      for (int k = 0; k < 4; ++k)
        g[k] = (float)xp15[(size_t)n * 2048 + k * 512 + j] + bhh[k * 512 + j];
      float cv = fast_sig(g[0]) * fast_tanh(g[2]);
      h0[(size_t)n * HIDDEN + j] = (bf16)(fast_sig(g[3]) * fast_tanh(cv));
      c0[(size_t)n * HIDDEN + j] = cv;
    }
  }
  grid.sync();

  bf16* hb[2] = {h0, h1};
  float* cb[2] = {c0, c1};
  int cur = 0;
  for (int lvl = 14; lvl >= 0; --lvl) {
    tree_level_body(bm0, j0, fl, lvl, map, hb[cur], cb[cur], W, bhh,
                    xp + (size_t)lvl * lvl_sz, cb[cur ^ 1], hb[cur ^ 1],
                    (lvl == 0) ? h_f32 : nullptr, sA, sB);
    if (lvl > 0) grid.sync();
    cur ^= 1;
  }
}

// ---------------- fallback per-level kernels (if coop launch unavailable) --
__global__ __launch_bounds__(256, 2) void cell_tree_f(
    const int* __restrict__ map, const int* __restrict__ flags, int level,
    const bf16* __restrict__ h_src, const float* __restrict__ c_src,
    const bf16* __restrict__ W, const float* __restrict__ bhh,
    const bf16* __restrict__ xp,
    float* __restrict__ c_out, bf16* __restrict__ h_out,
    float* __restrict__ h_f32)
{
  __shared__ __align__(16) bf16 sA[32 * 512];
  __shared__ __align__(16) bf16 sB[128 * 64];
  tree_level_body(blockIdx.x * 32, blockIdx.y * 32, flags[0], level, map,
                  h_src, c_src, W, bhh, xp, c_out, h_out, h_f32, sA, sB);
}

__global__ void cell0(const bf16* __restrict__ xp,
                      const float* __restrict__ bhh,
                      bf16* __restrict__ h, float* __restrict__ c)
{
  int n = blockIdx.x, j = threadIdx.x;
  float g[4];
#pragma unroll
  for (int k = 0; k < 4; ++k)
    g[k] = (float)xp[(size_t)n * 2048 + k * 512 + j] + bhh[k * 512 + j];
  float cv = fast_sig(g[0]) * fast_tanh(g[2]);
  h[(size_t)n * HIDDEN + j] = (bf16)(fast_sig(g[3]) * fast_tanh(cv));
  c[(size_t)n * HIDDEN + j] = cv;
}

// ---------------- plain GEMM (BK=32, swizzled): concat(A0,A1,A2)·B^T -------
template <int MT>
__global__ __launch_bounds__(256, 2) void plain_gemm(
    const bf16* __restrict__ A0, int a0s, int a0kt,
    const bf16* __restrict__ A1, int a1s, int a1kt,
    const bf16* __restrict__ A2, int a2s, int a2kt,
    const bf16* __restrict__ B, int bs,
    const float* __restrict__ bias, int do_relu,
    bf16* __restrict__ outh, int Ntot)
{
  constexpr int BM = MT * 32;
  __shared__ __align__(16) bf16 sA[BM * 32];
  __shared__ __align__(16) bf16 sB[128 * 32];
  const int tid = threadIdx.x;
  const int lane = tid & 63;
  const int quad = lane >> 4, cl = lane & 15;
  const int wave = tid >> 6;
  const int wr = wave >> 1, wc = wave & 1;
  const int bm0 = blockIdx.x * BM;
  const int bn0 = blockIdx.y * 128;

  f32x4 acc[MT][4];
#pragma unroll
  for (int mi = 0; mi < MT; ++mi)
#pragma unroll
    for (int ni = 0; ni < 4; ++ni) acc[mi][ni] = f32x4{0.f, 0.f, 0.f, 0.f};

  const int nkt = a0kt + a1kt + a2kt;
  for (int kt = 0; kt < nkt; ++kt) {
    const bf16* abase; int astr, acol;
    if (kt < a0kt)            { abase = A0; astr = a0s; acol = kt * 32; }
    else if (kt < a0kt + a1kt){ abase = A1; astr = a1s; acol = (kt - a0kt) * 32; }
    else                      { abase = A2; astr = a2s; acol = (kt - a0kt - a1kt) * 32; }
#pragma unroll
    for (int ia = 0; ia < MT / 2; ++ia) {
      int e = ia * 256 + tid;
      int row = e >> 2, sl = e & 3;
      int src = sl ^ ((row >> 1) & 3);
      async16(abase + (size_t)(bm0 + row) * astr + acol + src * 8, sA + e * 8);
    }
#pragma unroll
    for (int ib = 0; ib < 2; ++ib) {
      int e = ib * 256 + tid;
      int row = e >> 2, sl = e & 3;
      int src = sl ^ ((row >> 1) & 3);
      async16(B + (size_t)(bn0 + row) * bs + kt * 32 + src * 8, sB + e * 8);
    }
    __syncthreads();
    bf16x8 af[MT], bfr[4];
#pragma unroll
    for (int mi = 0; mi < MT; ++mi) {
      int row = wr * (MT * 16) + mi * 16 + cl;
      int sl = quad ^ ((row >> 1) & 3);
      af[mi] = *(const bf16x8*)&sA[row * 32 + sl * 8];
    }
#pragma unroll
    for (int ni = 0; ni < 4; ++ni) {
      int row = wc * 64 + ni * 16 + cl;
      int sl = quad ^ ((row >> 1) & 3);
      bfr[ni] = *(const bf16x8*)&sB[row * 32 + sl * 8];
    }
#pragma unroll
    for (int mi = 0; mi < MT; ++mi)
#pragma unroll
      for (int ni = 0; ni < 4; ++ni)
        acc[mi][ni] = __builtin_amdgcn_mfma_f32_16x16x32_bf16(af[mi], bfr[ni], acc[mi][ni], 0, 0, 0);
    __syncthreads();
  }

#pragma unroll
  for (int mi = 0; mi < MT; ++mi) {
    int rb = bm0 + wr * (MT * 16) + mi * 16 + quad * 4;
#pragma unroll
    for (int ni = 0; ni < 4; ++ni) {
      int col = bn0 + wc * 64 + ni * 16 + cl;
      float bv = bias ? bias[col] : 0.f;
#pragma unroll
      for (int r = 0; r < 4; ++r) {
        int row = rb + r;
        float v = acc[mi][ni][r] + bv;
        if (do_relu) v = fmaxf(v, 0.f);
        outh[(size_t)row * Ntot + col] = (bf16)v;
      }
    }
  }
}

// ---------------- deterministic batchnorm ----------------
__global__ void bn_reduce_b16(const bf16* __restrict__ x, int rpb, int F,
                              float* __restrict__ partials) {
  int col = threadIdx.x, b = blockIdx.x;
  const bf16* p = x + (size_t)b * rpb * F + col;
  float s = 0.f, q = 0.f;
  for (int r = 0; r < rpb; ++r) { float v = (float)p[(size_t)r * F]; s += v; q += v * v; }
  partials[(size_t)b * 2 * F + col] = s;
  partials[(size_t)b * 2 * F + F + col] = q;
}

__global__ void bn_reduce_f32(const float* __restrict__ x, int rpb, int F,
                              float* __restrict__ partials) {
  int col = threadIdx.x, b = blockIdx.x;
  const float* p = x + (size_t)b * rpb * F + col;
  float s = 0.f, q = 0.f;
  for (int r = 0; r < rpb; ++r) { float v = p[(size_t)r * F]; s += v; q += v * v; }
  partials[(size_t)b * 2 * F + col] = s;
  partials[(size_t)b * 2 * F + F + col] = q;
}

__global__ void bn_final(const float* __restrict__ partials, int nb, int F,
                         const float* __restrict__ g, const float* __restrict__ b,
                         float invB, float* __restrict__ scale, float* __restrict__ shift) {
  int j = threadIdx.x;
  float s = 0.f, q = 0.f;
  for (int i = 0; i < nb; ++i) {
    s += partials[(size_t)i * 2 * F + j];
    q += partials[(size_t)i * 2 * F + F + j];
  }
  float mu = s * invB;
  float var = fmaxf(q * invB - mu * mu, 0.f);
  float sc = g[j] * rsqrtf(var + 1e-5f);
  scale[j] = sc;
  shift[j] = b[j] - sc * mu;
}

__global__ void bn_apply_mid(const bf16* __restrict__ x, const float* __restrict__ scale,
                             const float* __restrict__ shift, int Fmask, size_t total,
                             bf16* __restrict__ out) {
  for (size_t i = blockIdx.x * (size_t)blockDim.x + threadIdx.x; i < total;
       i += (size_t)gridDim.x * blockDim.x) {
    int j = (int)(i & (size_t)Fmask);
    out[i] = (bf16)(scale[j] * (float)x[i] + shift[j]);
  }
}

__global__ void bn_apply_out(const float* __restrict__ x, const float* __restrict__ scale,
                             const float* __restrict__ shift, int Fmask, size_t total,
                             float* __restrict__ out) {
  for (size_t i = blockIdx.x * (size_t)blockDim.x + threadIdx.x; i < total;
       i += (size_t)gridDim.x * blockDim.x) {
    int j = (int)(i & (size_t)Fmask);
    out[i] = scale[j] * x[i] + shift[j];
  }
}

// ---------------------------------------------------------------------------
extern "C" void kernel_launch(void* const* d_in, const int* in_sizes, int n_in,
                              void* d_out, int out_size, void* d_ws, size_t ws_size,
                              hipStream_t stream) {
  const float* operators = (const float*)d_in[0];
  const float* extras    = (const float*)d_in[1];
  const float* conds     = (const float*)d_in[2];
  const int*   mapping   = (const int*)d_in[4];
  const float* b1ih = (const float*)d_in[7];
  const float* b1hh = (const float*)d_in[8];
  const float* condb = (const float*)d_in[10];
  const float* bn1g = (const float*)d_in[11];
  const float* bn1b = (const float*)d_in[12];
  const float* b2ih = (const float*)d_in[15];
  const float* b2hh = (const float*)d_in[16];
  const float* bn2g = (const float*)d_in[17];
  const float* bn2b = (const float*)d_in[18];

  char* ws = (char*)d_ws;
  size_t o = 0;
  auto alloc = [&](size_t bytes) {
    char* p = ws + o;
    o += (bytes + 255) & ~(size_t)255;
    return p;
  };
  bf16* conds_b = (bf16*)alloc((size_t)33554432 * 2);
  bf16* ops_b   = (bf16*)alloc((size_t)524288 * 2);
  bf16* ext_b   = (bf16*)alloc((size_t)524288 * 2);
  bf16* w1ih_b  = (bf16*)alloc((size_t)524288 * 2);
  bf16* w1hh_b  = (bf16*)alloc((size_t)1048576 * 2);
  bf16* condw_b = (bf16*)alloc((size_t)131072 * 2);
  bf16* w2ih_b  = (bf16*)alloc((size_t)655360 * 2);
  bf16* w2hh_b  = (bf16*)alloc((size_t)1048576 * 2);
  bf16* h1[2];
  h1[0] = (bf16*)alloc((size_t)16384 * 512 * 2);
  h1[1] = (bf16*)alloc((size_t)16384 * 512 * 2);
  float* c1 = (float*)alloc((size_t)16384 * 512 * 4);
  bf16* last_relu = (bf16*)alloc((size_t)16384 * 256 * 2);
  bf16* last_bn = (bf16*)alloc((size_t)16384 * 256 * 2);
  bf16* hbuf0 = (bf16*)alloc((size_t)1024 * 512 * 2);
  bf16* hbuf1 = (bf16*)alloc((size_t)1024 * 512 * 2);
  float* cbuf0 = (float*)alloc((size_t)1024 * 512 * 4);
  float* cbuf1 = (float*)alloc((size_t)1024 * 512 * 4);
  float* h2f = (float*)alloc((size_t)1024 * 512 * 4);
  float* partials = (float*)alloc((size_t)64 * 1024 * 4);
  float* scale1 = (float*)alloc(256 * 4);
  float* shift1 = (float*)alloc(256 * 4);
  float* scale2 = (float*)alloc(512 * 4);
  float* shift2 = (float*)alloc(512 * 4);
  int* flags = (int*)alloc(256);
  bf16* xp2 = (bf16*)alloc((size_t)16384 * 2048 * 2);

  prep<<<18561, 256, 0, stream>>>(
      conds, conds_b,
      operators, ops_b, extras, ext_b,
      (const float*)d_in[5], w1ih_b, (const float*)d_in[6], w1hh_b,
      (const float*)d_in[9], condw_b, (const float*)d_in[13], w2ih_b,
      (const float*)d_in[14], w2hh_b,
      mapping, flags);

  // -------- LSTM1: 8 fused K=768 GEMM+cell steps (BM=128 x BN=256) --------
  cell_gemm<4, 4, 0><<<dim3(128, 8), 256, 0, stream>>>(
      conds_b, 0, 2048, nullptr, 512,
      w1ih_b, 256, w1hh_b, 512,
      b1ih, b1hh, nullptr, c1, h1[1]);
  for (int t = 1; t < 8; ++t) {
    cell_gemm<4, 4, 8><<<dim3(128, 8), 256, 0, stream>>>(
        conds_b, t * 256, 2048, h1[t & 1], 512,
        w1ih_b, 256, w1hh_b, 512,
        b1ih, b1hh, c1, c1, h1[(t + 1) & 1]);
  }

  // -------- last = relu(h1 @ condW^T + condb); BN1 --------
  plain_gemm<2><<<dim3(256, 2), 256, 0, stream>>>(
      h1[0], 512, 16, nullptr, 0, 0, nullptr, 0, 0,
      condw_b, 512, condb, 1, last_relu, 256);
  bn_reduce_b16<<<64, 256, 0, stream>>>(last_relu, 256, 256, partials);
  bn_final<<<1, 256, 0, stream>>>(partials, 64, 256, bn1g, bn1b, 1.f / 16384.f, scale1, shift1);
  bn_apply_mid<<<1024, 256, 0, stream>>>(last_relu, scale1, shift1, 255,
                                         (size_t)16384 * 256, last_bn);

  // -------- xp2 = concat(ops, extras, last_bn) @ W2ih^T + b2ih (bf16) -----
  plain_gemm<4><<<dim3(128, 16), 256, 0, stream>>>(
      ops_b, 32, 1, ext_b, 32, 1, last_bn, 256, 8,
      w2ih_b, 320, b2ih, 0, xp2, 2048);

  // -------- LSTM2 tree: ONE cooperative kernel (fallback: per-level) ------
  size_t lvl_sz = (size_t)1024 * 2048;
  {
    const int* a_map = mapping; const int* a_flags = flags;
    const bf16* a_xp = xp2; const float* a_bhh = b2hh; const bf16* a_W = w2hh_b;
    bf16* a_h0 = hbuf0; bf16* a_h1 = hbuf1;
    float* a_c0 = cbuf0; float* a_c1 = cbuf1; float* a_hf = h2f;
    void* cargs[] = {(void*)&a_map, (void*)&a_flags, (void*)&a_xp, (void*)&a_bhh,
                     (void*)&a_W, (void*)&a_h0, (void*)&a_h1, (void*)&a_c0,
                     (void*)&a_c1, (void*)&a_hf};
    hipError_t cerr = hipLaunchCooperativeKernel(
        (const void*)tree_fused, dim3(512), dim3(256), cargs, 0, stream);
    if (cerr != hipSuccess) {
      (void)hipGetLastError();  // clear sticky error, use fallback path
      bf16* hb[2] = {hbuf0, hbuf1};
      float* cb[2] = {cbuf0, cbuf1};
      cell0<<<1024, 512, 0, stream>>>(xp2 + 15 * lvl_sz, b2hh, hb[0], cb[0]);
      int cur = 0;
      for (int idx = 14; idx >= 0; --idx) {
        int nxt = cur ^ 1;
        cell_tree_f<<<dim3(32, 16), 256, 0, stream>>>(
            mapping, flags, idx, hb[cur], cb[cur], w2hh_b, b2hh,
            xp2 + (size_t)idx * lvl_sz, cb[nxt], hb[nxt],
            (idx == 0) ? h2f : nullptr);
        cur = nxt;
      }
    }
  }

  // -------- BN2 -> output --------
  bn_reduce_f32<<<16, 512, 0, stream>>>(h2f, 64, 512, partials);
  bn_final<<<1, 512, 0, stream>>>(partials, 16, 512, bn2g, bn2b, 1.f / 1024.f, scale2, shift2);
  bn_apply_out<<<512, 256, 0, stream>>>(h2f, scale2, shift2, 511,
                                        (size_t)1024 * 512, (float*)d_out);
}

// Round 9
// 1121.441 us; speedup vs baseline: 1.8230x; 1.8230x over previous
//
#include <hip/hip_runtime.h>
#include <hip/hip_bf16.h>
#include <stdint.h>

// ---------------------------------------------------------------------------
// E2E: LSTM1(8 steps) -> relu(linear)+BN1 -> concat -> xp2 -> LSTM2 tree(16)
//      -> BN2 -> out [1024,512] f32.
// R17 (2nd resubmit; R7+R8 benches were acquisition timeouts, never ran):
// revert to R12 structure (best measured; coop grid.sync measured at
// ~60us/sync on 8-XCD -> dead). New: (a) tree epilogue de-scattered - c-avg,
// map and xp tile staged into LDS during gather phase (coalesced), epilogue
// reads LDS; (b) BN1 folded into xp2 weights (fold_w2 kernel), bn_apply_mid
// removed, xp2 GEMM reads last_relu directly.
// ---------------------------------------------------------------------------

typedef __bf16 bf16;
typedef __bf16 bf16x8 __attribute__((ext_vector_type(8)));
typedef float f32x4 __attribute__((ext_vector_type(4)));

#define HIDDEN 512

__device__ __forceinline__ float fast_sig(float x) { return 1.f / (1.f + __expf(-x)); }
__device__ __forceinline__ float fast_tanh(float x) {
  float e = __expf(2.f * x);
  return 1.f - 2.f / (e + 1.f);
}

__device__ __forceinline__ void async16(const bf16* g, bf16* l) {
  __builtin_amdgcn_global_load_lds(
      (const __attribute__((address_space(1))) void*)g,
      (__attribute__((address_space(3))) void*)l, 16, 0, 0);
}

// ---------------- merged prep: cvts + detect ----------------
__device__ __forceinline__ void cvt_one(const float* __restrict__ src,
                                        bf16* __restrict__ dst, size_t i) {
  float4 a = *(const float4*)(src + i);
  float4 b = *(const float4*)(src + i + 4);
  bf16x8 r;
  r[0] = (bf16)a.x; r[1] = (bf16)a.y; r[2] = (bf16)a.z; r[3] = (bf16)a.w;
  r[4] = (bf16)b.x; r[5] = (bf16)b.y; r[6] = (bf16)b.z; r[7] = (bf16)b.w;
  *(bf16x8*)(dst + i) = r;
}

__global__ void prep(const float* conds, bf16* conds_b,
                     const float* s0, bf16* d0, const float* s1, bf16* d1,
                     const float* s2, bf16* d2, const float* s3, bf16* d3,
                     const float* s4, bf16* d4, const float* s5, bf16* d5,
                     const float* s6, bf16* d6,
                     const int* map, int* flags) {
  int b = blockIdx.x;
  int tid = threadIdx.x;
  if (b < 2176) {
    int g = b * 256 + tid;
    const float* s; bf16* d; int off;
    if      (g < 65536)  { s = s0; d = d0; off = g; }
    else if (g < 131072) { s = s1; d = d1; off = g - 65536; }
    else if (g < 196608) { s = s2; d = d2; off = g - 131072; }
    else if (g < 327680) { s = s3; d = d3; off = g - 196608; }
    else if (g < 344064) { s = s4; d = d4; off = g - 327680; }
    else if (g < 425984) { s = s5; d = d5; off = g - 344064; }
    else if (g < 557056) { s = s6; d = d6; off = g - 425984; }
    else return;
    cvt_one(s, d, (size_t)off * 8);
  } else if (b == 2176) {
    __shared__ int any;
    if (tid == 0) any = 0;
    __syncthreads();
    int loc = 0;
    for (int i = tid; i < 16384; i += 256) loc |= map[2 * i + 1];
    if (loc) atomicOr(&any, 1);
    __syncthreads();
    if (tid == 0) flags[0] = (any == 0) ? 1 : 0;
  } else {
    size_t i = ((size_t)(b - 2177) * 256 + tid) * 8;
    cvt_one(conds, conds_b, i);
  }
}

// ---------------- LSTM1 fused GEMM + cell (BM=128 x BN=256, BK=64) ---------
// R12 variant (best measured). B-tile: 256 rows = 4 gates x 64 j-cols.
template <int MT, int KT0, int KT1>
__global__ __launch_bounds__(256, 2) void cell_gemm(
    const bf16* __restrict__ A0, int a0off, int a0s,
    const bf16* __restrict__ A1, int a1s,
    const bf16* __restrict__ B0, int b0s,
    const bf16* __restrict__ B1, int b1s,
    const float* __restrict__ bias0, const float* __restrict__ bias1,
    const float* __restrict__ c_prev,
    float* __restrict__ c_out,
    bf16* __restrict__ h_b16)
{
  constexpr int BM = MT * 32;
  __shared__ __align__(16) bf16 sA[BM * 64];
  __shared__ __align__(16) bf16 sB[256 * 64];
  const int tid = threadIdx.x;
  const int lane = tid & 63;
  const int quad = lane >> 4, cl = lane & 15;
  const int wave = tid >> 6;
  const int wr = wave >> 1, wc = wave & 1;
  const int bm0 = blockIdx.x * BM;
  const int j0 = blockIdx.y * 64;

  const bf16* ra[MT][2];
  const bf16* rb[8][2];
#pragma unroll
  for (int mi = 0; mi < MT; ++mi)
#pragma unroll
    for (int kh = 0; kh < 2; ++kh) {
      int row = wr * (MT * 16) + mi * 16 + cl;
      ra[mi][kh] = &sA[row * 64 + (((kh * 4 + quad) ^ (row & 7))) * 8];
    }
#pragma unroll
  for (int g = 0; g < 8; ++g)
#pragma unroll
    for (int kh = 0; kh < 2; ++kh) {
      int row = g * 32 + wc * 16 + cl;
      rb[g][kh] = &sB[row * 64 + (((kh * 4 + quad) ^ (row & 7))) * 8];
    }

  f32x4 acc[MT][8];
#pragma unroll
  for (int mi = 0; mi < MT; ++mi)
#pragma unroll
    for (int g = 0; g < 8; ++g) acc[mi][g] = f32x4{0.f, 0.f, 0.f, 0.f};

  const bf16* pa[MT];
  const bf16* pb[8];
#pragma unroll
  for (int ia = 0; ia < MT; ++ia) {
    int e = ia * 256 + tid, row = e >> 3, sl = e & 7;
    pa[ia] = A0 + (size_t)((bm0 + row) * a0s + a0off + (sl ^ (row & 7)) * 8);
  }
#pragma unroll
  for (int ib = 0; ib < 8; ++ib) {
    int e = ib * 256 + tid, row = e >> 3, sl = e & 7;
    int wrow = (row >> 6) * HIDDEN + j0 + (row & 63);
    pb[ib] = B0 + (size_t)(wrow * b0s + (sl ^ (row & 7)) * 8);
  }

  auto ktile = [&]() {
#pragma unroll
    for (int ia = 0; ia < MT; ++ia) {
      async16(pa[ia], sA + (ia * 256 + tid) * 8);
      pa[ia] += 64;
    }
#pragma unroll
    for (int ib = 0; ib < 8; ++ib) {
      async16(pb[ib], sB + (ib * 256 + tid) * 8);
      pb[ib] += 64;
    }
    __syncthreads();
#pragma unroll
    for (int kh = 0; kh < 2; ++kh) {
      bf16x8 af[MT], bfr[8];
#pragma unroll
      for (int mi = 0; mi < MT; ++mi) af[mi] = *(const bf16x8*)ra[mi][kh];
#pragma unroll
      for (int g = 0; g < 8; ++g) bfr[g] = *(const bf16x8*)rb[g][kh];
#pragma unroll
      for (int mi = 0; mi < MT; ++mi)
#pragma unroll
        for (int g = 0; g < 8; ++g)
          acc[mi][g] = __builtin_amdgcn_mfma_f32_16x16x32_bf16(af[mi], bfr[g], acc[mi][g], 0, 0, 0);
    }
    __syncthreads();
  };

  for (int kt = 0; kt < KT0; ++kt) ktile();
  if (KT1 > 0) {
#pragma unroll
    for (int ia = 0; ia < MT; ++ia) {
      int e = ia * 256 + tid, row = e >> 3, sl = e & 7;
      pa[ia] = A1 + (size_t)((bm0 + row) * a1s + (sl ^ (row & 7)) * 8);
    }
#pragma unroll
    for (int ib = 0; ib < 8; ++ib) {
      int e = ib * 256 + tid, row = e >> 3, sl = e & 7;
      int wrow = (row >> 6) * HIDDEN + j0 + (row & 63);
      pb[ib] = B1 + (size_t)(wrow * b1s + (sl ^ (row & 7)) * 8);
    }
    for (int kt = 0; kt < KT1; ++kt) ktile();
  }

#pragma unroll
  for (int h = 0; h < 2; ++h) {
    const int j = j0 + h * 32 + wc * 16 + cl;
    float bI = bias0[j] + bias1[j];
    float bF = bias0[HIDDEN + j] + bias1[HIDDEN + j];
    float bG = bias0[2 * HIDDEN + j] + bias1[2 * HIDDEN + j];
    float bO = bias0[3 * HIDDEN + j] + bias1[3 * HIDDEN + j];
#pragma unroll
    for (int mi = 0; mi < MT; ++mi) {
      int rb_ = bm0 + wr * (MT * 16) + mi * 16 + quad * 4;
#pragma unroll
      for (int r = 0; r < 4; ++r) {
        int row = rb_ + r;
        float iv = fast_sig(acc[mi][0 + h][r] + bI);
        float fv = fast_sig(acc[mi][2 + h][r] + bF);
        float gv = fast_tanh(acc[mi][4 + h][r] + bG);
        float ov = fast_sig(acc[mi][6 + h][r] + bO);
        float cp = c_prev ? c_prev[(size_t)row * HIDDEN + j] : 0.f;
        float cn = fv * cp + iv * gv;
        float hn = ov * fast_tanh(cn);
        c_out[(size_t)row * HIDDEN + j] = cn;
        h_b16[(size_t)row * HIDDEN + j] = (bf16)hn;
      }
    }
  }
}

// ---------------- fused tree cell: gather(avg) -> GEMM -> cell -------------
// Gather phase stages: h-avg into sA (MFMA-swizzled), c-avg into cavg LDS
// (coalesced float4), xp tile into sXP (coalesced bf16x8). Epilogue is
// LDS-only (no scattered global reads).
__global__ __launch_bounds__(256, 2) void cell_tree_f(
    const int* __restrict__ map, const int* __restrict__ flags, int level,
    const bf16* __restrict__ h_src, const float* __restrict__ c_src,
    const bf16* __restrict__ W, const float* __restrict__ bhh,
    const bf16* __restrict__ xp,
    float* __restrict__ c_out, bf16* __restrict__ h_out,
    float* __restrict__ h_f32)
{
  __shared__ __align__(16) bf16 sA[32 * 512];       // gathered h-avg
  __shared__ __align__(16) bf16 sB[128 * 64];       // W k-tile
  __shared__ __align__(16) float cavg[32 * 33];     // gathered c-avg (padded)
  __shared__ __align__(16) bf16 sXP[32 * 4 * 32];   // xp tile [row][gate][col]
  const int tid = threadIdx.x;
  const int lane = tid & 63;
  const int quad = lane >> 4, cl = lane & 15;
  const int wave = tid >> 6;
  const int wr = wave >> 1, wc = wave & 1;
  const int bm0 = blockIdx.x * 32;
  const int j0 = blockIdx.y * 32;
  const int fl = flags[0];

  // ---- gather phase ----
  {
    int grow = tid >> 3;        // 0..31
    int w = tid & 7;
    int n = bm0 + grow;
    long mbase = (long)level * 2048 + n * 2;
    int m0, m1;
    if (fl) { m0 = map[mbase * 2]; m1 = map[mbase * 2 + 2]; }
    else    { m0 = map[mbase];     m1 = map[mbase + 1]; }
    const bf16* s0 = h_src + (size_t)(m0 ? m0 - 1 : 0) * HIDDEN;
    const bf16* s1 = h_src + (size_t)(m1 ? m1 - 1 : 0) * HIDDEN;
    float f0 = m0 ? 0.5f : 0.f;
    float f1 = m1 ? 0.5f : 0.f;
    int sw = grow & 7;
    bf16* drow = sA + grow * 512;
#pragma unroll
    for (int g = 0; g < 8; ++g) {
      int slot = g * 8 + w;
      bf16x8 a = *(const bf16x8*)(s0 + slot * 8);
      bf16x8 b = *(const bf16x8*)(s1 + slot * 8);
      bf16x8 r;
#pragma unroll
      for (int e = 0; e < 8; ++e)
        r[e] = (bf16)(f0 * (float)a[e] + f1 * (float)b[e]);
      *(bf16x8*)(drow + (g * 8 + (w ^ sw)) * 8) = r;
    }
    // c-avg for this block's j-slice: 4 cols per thread (float4, coalesced)
    {
      int cj = j0 + w * 4;
      float4 c0 = m0 ? *(const float4*)(c_src + (size_t)(m0 - 1) * HIDDEN + cj)
                     : float4{0.f, 0.f, 0.f, 0.f};
      float4 c1 = m1 ? *(const float4*)(c_src + (size_t)(m1 - 1) * HIDDEN + cj)
                     : float4{0.f, 0.f, 0.f, 0.f};
      float* cd = cavg + grow * 33 + w * 4;
      cd[0] = 0.5f * (c0.x + c1.x);
      cd[1] = 0.5f * (c0.y + c1.y);
      cd[2] = 0.5f * (c0.z + c1.z);
      cd[3] = 0.5f * (c0.w + c1.w);
    }
    // xp tile: rows bm0..+31, 4 gates, cols j0..+31 (2 bf16x8 per thread)
    {
      const bf16* xr = xp + (size_t)n * 2048;
      int gate = w >> 1, half = w & 1;
      bf16x8 v0 = *(const bf16x8*)(xr + gate * HIDDEN + j0 + half * 16);
      bf16x8 v1 = *(const bf16x8*)(xr + gate * HIDDEN + j0 + half * 16 + 8);
      bf16* xd = sXP + (grow * 4 + gate) * 32 + half * 16;
      *(bf16x8*)xd = v0;
      *(bf16x8*)(xd + 8) = v1;
    }
  }

  // ---- fragment pointers ----
  const bf16* ra[2];
#pragma unroll
  for (int kh = 0; kh < 2; ++kh) {
    int row = wr * 16 + cl;
    ra[kh] = &sA[row * 512 + (((kh * 4 + quad) ^ (row & 7))) * 8];
  }
  const bf16* rb[4][2];
#pragma unroll
  for (int g = 0; g < 4; ++g)
#pragma unroll
    for (int kh = 0; kh < 2; ++kh) {
      int row = g * 32 + wc * 16 + cl;
      rb[g][kh] = &sB[row * 64 + (((kh * 4 + quad) ^ (row & 7))) * 8];
    }

  f32x4 acc[4];
#pragma unroll
  for (int g = 0; g < 4; ++g) acc[g] = f32x4{0.f, 0.f, 0.f, 0.f};

  const bf16* pb[4];
#pragma unroll
  for (int ib = 0; ib < 4; ++ib) {
    int e = ib * 256 + tid, row = e >> 3, sl = e & 7;
    int wrow = (row >> 5) * HIDDEN + j0 + (row & 31);
    pb[ib] = W + (size_t)(wrow * HIDDEN + (sl ^ (row & 7)) * 8);
  }

  for (int kt = 0; kt < 8; ++kt) {
#pragma unroll
    for (int ib = 0; ib < 4; ++ib) {
      async16(pb[ib], sB + (ib * 256 + tid) * 8);
      pb[ib] += 64;
    }
    __syncthreads();   // covers gather ds_writes on kt==0, B staging always
#pragma unroll
    for (int kh = 0; kh < 2; ++kh) {
      bf16x8 af = *(const bf16x8*)(ra[kh] + kt * 64);
#pragma unroll
      for (int g = 0; g < 4; ++g) {
        bf16x8 bfr = *(const bf16x8*)rb[g][kh];
        acc[g] = __builtin_amdgcn_mfma_f32_16x16x32_bf16(af, bfr, acc[g], 0, 0, 0);
      }
    }
    __syncthreads();
  }

  // ---- epilogue: all operands from LDS ----
  const int jl = wc * 16 + cl;
  const int j = j0 + jl;
  float bI = bhh[j], bF = bhh[HIDDEN + j];
  float bG = bhh[2 * HIDDEN + j], bO = bhh[3 * HIDDEN + j];
  int rl0 = wr * 16 + quad * 4;
#pragma unroll
  for (int r = 0; r < 4; ++r) {
    int rl = rl0 + r;
    int row = bm0 + rl;
    float cp = cavg[rl * 33 + jl];
    const bf16* xr = sXP + rl * 128;
    float gi = acc[0][r] + bI + (float)xr[jl];
    float gf = acc[1][r] + bF + (float)xr[32 + jl];
    float gg = acc[2][r] + bG + (float)xr[64 + jl];
    float go = acc[3][r] + bO + (float)xr[96 + jl];
    float cn = fast_sig(gf) * cp + fast_sig(gi) * fast_tanh(gg);
    float hn = fast_sig(go) * fast_tanh(cn);
    c_out[(size_t)row * HIDDEN + j] = cn;
    h_out[(size_t)row * HIDDEN + j] = (bf16)hn;
    if (h_f32) h_f32[(size_t)row * HIDDEN + j] = hn;
  }
}

// level-15 cell: zero state -> gates = xp2[15] + bhh
__global__ void cell0(const bf16* __restrict__ xp,
                      const float* __restrict__ bhh,
                      bf16* __restrict__ h, float* __restrict__ c)
{
  int n = blockIdx.x, j = threadIdx.x;
  float g[4];
#pragma unroll
  for (int k = 0; k < 4; ++k)
    g[k] = (float)xp[(size_t)n * 2048 + k * 512 + j] + bhh[k * 512 + j];
  float cv = fast_sig(g[0]) * fast_tanh(g[2]);
  h[(size_t)n * HIDDEN + j] = (bf16)(fast_sig(g[3]) * fast_tanh(cv));
  c[(size_t)n * HIDDEN + j] = cv;
}

// ---------------- plain GEMM (BK=32, swizzled): concat(A0,A1,A2)·B^T -------
template <int MT>
__global__ __launch_bounds__(256, 2) void plain_gemm(
    const bf16* __restrict__ A0, int a0s, int a0kt,
    const bf16* __restrict__ A1, int a1s, int a1kt,
    const bf16* __restrict__ A2, int a2s, int a2kt,
    const bf16* __restrict__ B, int bs,
    const float* __restrict__ bias, int do_relu,
    bf16* __restrict__ outh, int Ntot)
{
  constexpr int BM = MT * 32;
  __shared__ __align__(16) bf16 sA[BM * 32];
  __shared__ __align__(16) bf16 sB[128 * 32];
  const int tid = threadIdx.x;
  const int lane = tid & 63;
  const int quad = lane >> 4, cl = lane & 15;
  const int wave = tid >> 6;
  const int wr = wave >> 1, wc = wave & 1;
  const int bm0 = blockIdx.x * BM;
  const int bn0 = blockIdx.y * 128;

  f32x4 acc[MT][4];
#pragma unroll
  for (int mi = 0; mi < MT; ++mi)
#pragma unroll
    for (int ni = 0; ni < 4; ++ni) acc[mi][ni] = f32x4{0.f, 0.f, 0.f, 0.f};

  const int nkt = a0kt + a1kt + a2kt;
  for (int kt = 0; kt < nkt; ++kt) {
    const bf16* abase; int astr, acol;
    if (kt < a0kt)            { abase = A0; astr = a0s; acol = kt * 32; }
    else if (kt < a0kt + a1kt){ abase = A1; astr = a1s; acol = (kt - a0kt) * 32; }
    else                      { abase = A2; astr = a2s; acol = (kt - a0kt - a1kt) * 32; }
#pragma unroll
    for (int ia = 0; ia < MT / 2; ++ia) {
      int e = ia * 256 + tid;
      int row = e >> 2, sl = e & 3;
      int src = sl ^ ((row >> 1) & 3);
      async16(abase + (size_t)(bm0 + row) * astr + acol + src * 8, sA + e * 8);
    }
#pragma unroll
    for (int ib = 0; ib < 2; ++ib) {
      int e = ib * 256 + tid;
      int row = e >> 2, sl = e & 3;
      int src = sl ^ ((row >> 1) & 3);
      async16(B + (size_t)(bn0 + row) * bs + kt * 32 + src * 8, sB + e * 8);
    }
    __syncthreads();
    bf16x8 af[MT], bfr[4];
#pragma unroll
    for (int mi = 0; mi < MT; ++mi) {
      int row = wr * (MT * 16) + mi * 16 + cl;
      int sl = quad ^ ((row >> 1) & 3);
      af[mi] = *(const bf16x8*)&sA[row * 32 + sl * 8];
    }
#pragma unroll
    for (int ni = 0; ni < 4; ++ni) {
      int row = wc * 64 + ni * 16 + cl;
      int sl = quad ^ ((row >> 1) & 3);
      bfr[ni] = *(const bf16x8*)&sB[row * 32 + sl * 8];
    }
#pragma unroll
    for (int mi = 0; mi < MT; ++mi)
#pragma unroll
      for (int ni = 0; ni < 4; ++ni)
        acc[mi][ni] = __builtin_amdgcn_mfma_f32_16x16x32_bf16(af[mi], bfr[ni], acc[mi][ni], 0, 0, 0);
    __syncthreads();
  }

#pragma unroll
  for (int mi = 0; mi < MT; ++mi) {
    int rb = bm0 + wr * (MT * 16) + mi * 16 + quad * 4;
#pragma unroll
    for (int ni = 0; ni < 4; ++ni) {
      int col = bn0 + wc * 64 + ni * 16 + cl;
      float bv = bias ? bias[col] : 0.f;
#pragma unroll
      for (int r = 0; r < 4; ++r) {
        int row = rb + r;
        float v = acc[mi][ni][r] + bv;
        if (do_relu) v = fmaxf(v, 0.f);
        outh[(size_t)row * Ntot + col] = (bf16)v;
      }
    }
  }
}

// ---------------- BN1 weight fold: W'[g,64+k]=W*s_k; bias'[g]=b+Σ t_k W ----
__global__ void fold_w2(const bf16* __restrict__ w2,      // [2048][320]
                        const float* __restrict__ scale,  // [256]
                        const float* __restrict__ shift,  // [256]
                        const float* __restrict__ b2ih,   // [2048]
                        bf16* __restrict__ w2f, float* __restrict__ bias2f) {
  int g = blockIdx.x * 8 + (threadIdx.x >> 5);
  int ln = threadIdx.x & 31;
  const bf16* src = w2 + (size_t)g * 320;
  bf16* dst = w2f + (size_t)g * 320;
  dst[ln] = src[ln];
  dst[32 + ln] = src[32 + ln];
  float acc = 0.f;
#pragma unroll
  for (int i = 0; i < 8; ++i) {
    int k = i * 32 + ln;
    float w = (float)src[64 + k];
    dst[64 + k] = (bf16)(w * scale[k]);
    acc += w * shift[k];
  }
#pragma unroll
  for (int off = 16; off; off >>= 1) acc += __shfl_down(acc, off, 32);
  if (ln == 0) bias2f[g] = b2ih[g] + acc;
}

// ---------------- deterministic batchnorm ----------------
__global__ void bn_reduce_b16(const bf16* __restrict__ x, int rpb, int F,
                              float* __restrict__ partials) {
  int col = threadIdx.x, b = blockIdx.x;
  const bf16* p = x + (size_t)b * rpb * F + col;
  float s = 0.f, q = 0.f;
  for (int r = 0; r < rpb; ++r) { float v = (float)p[(size_t)r * F]; s += v; q += v * v; }
  partials[(size_t)b * 2 * F + col] = s;
  partials[(size_t)b * 2 * F + F + col] = q;
}

__global__ void bn_reduce_f32(const float* __restrict__ x, int rpb, int F,
                              float* __restrict__ partials) {
  int col = threadIdx.x, b = blockIdx.x;
  const float* p = x + (size_t)b * rpb * F + col;
  float s = 0.f, q = 0.f;
  for (int r = 0; r < rpb; ++r) { float v = p[(size_t)r * F]; s += v; q += v * v; }
  partials[(size_t)b * 2 * F + col] = s;
  partials[(size_t)b * 2 * F + F + col] = q;
}

__global__ void bn_final(const float* __restrict__ partials, int nb, int F,
                         const float* __restrict__ g, const float* __restrict__ b,
                         float invB, float* __restrict__ scale, float* __restrict__ shift) {
  int j = threadIdx.x;
  float s = 0.f, q = 0.f;
  for (int i = 0; i < nb; ++i) {
    s += partials[(size_t)i * 2 * F + j];
    q += partials[(size_t)i * 2 * F + F + j];
  }
  float mu = s * invB;
  float var = fmaxf(q * invB - mu * mu, 0.f);
  float sc = g[j] * rsqrtf(var + 1e-5f);
  scale[j] = sc;
  shift[j] = b[j] - sc * mu;
}

__global__ void bn_apply_out(const float* __restrict__ x, const float* __restrict__ scale,
                             const float* __restrict__ shift, int Fmask, size_t total,
                             float* __restrict__ out) {
  for (size_t i = blockIdx.x * (size_t)blockDim.x + threadIdx.x; i < total;
       i += (size_t)gridDim.x * blockDim.x) {
    int j = (int)(i & (size_t)Fmask);
    out[i] = scale[j] * x[i] + shift[j];
  }
}

// ---------------------------------------------------------------------------
extern "C" void kernel_launch(void* const* d_in, const int* in_sizes, int n_in,
                              void* d_out, int out_size, void* d_ws, size_t ws_size,
                              hipStream_t stream) {
  const float* operators = (const float*)d_in[0];
  const float* extras    = (const float*)d_in[1];
  const float* conds     = (const float*)d_in[2];
  const int*   mapping   = (const int*)d_in[4];
  const float* b1ih = (const float*)d_in[7];
  const float* b1hh = (const float*)d_in[8];
  const float* condb = (const float*)d_in[10];
  const float* bn1g = (const float*)d_in[11];
  const float* bn1b = (const float*)d_in[12];
  const float* b2ih = (const float*)d_in[15];
  const float* b2hh = (const float*)d_in[16];
  const float* bn2g = (const float*)d_in[17];
  const float* bn2b = (const float*)d_in[18];

  char* ws = (char*)d_ws;
  size_t o = 0;
  auto alloc = [&](size_t bytes) {
    char* p = ws + o;
    o += (bytes + 255) & ~(size_t)255;
    return p;
  };
  bf16* conds_b = (bf16*)alloc((size_t)33554432 * 2);
  bf16* ops_b   = (bf16*)alloc((size_t)524288 * 2);
  bf16* ext_b   = (bf16*)alloc((size_t)524288 * 2);
  bf16* w1ih_b  = (bf16*)alloc((size_t)524288 * 2);
  bf16* w1hh_b  = (bf16*)alloc((size_t)1048576 * 2);
  bf16* condw_b = (bf16*)alloc((size_t)131072 * 2);
  bf16* w2ih_b  = (bf16*)alloc((size_t)655360 * 2);
  bf16* w2hh_b  = (bf16*)alloc((size_t)1048576 * 2);
  bf16* h1[2];
  h1[0] = (bf16*)alloc((size_t)16384 * 512 * 2);
  h1[1] = (bf16*)alloc((size_t)16384 * 512 * 2);
  float* c1 = (float*)alloc((size_t)16384 * 512 * 4);
  bf16* last_relu = (bf16*)alloc((size_t)16384 * 256 * 2);
  bf16* w2ih_f = (bf16*)alloc((size_t)655360 * 2);
  float* bias2f = (float*)alloc(2048 * 4);
  bf16* hbuf0 = (bf16*)alloc((size_t)1024 * 512 * 2);
  bf16* hbuf1 = (bf16*)alloc((size_t)1024 * 512 * 2);
  float* cbuf0 = (float*)alloc((size_t)1024 * 512 * 4);
  float* cbuf1 = (float*)alloc((size_t)1024 * 512 * 4);
  float* h2f = (float*)alloc((size_t)1024 * 512 * 4);
  float* partials = (float*)alloc((size_t)64 * 1024 * 4);
  float* scale1 = (float*)alloc(256 * 4);
  float* shift1 = (float*)alloc(256 * 4);
  float* scale2 = (float*)alloc(512 * 4);
  float* shift2 = (float*)alloc(512 * 4);
  int* flags = (int*)alloc(256);
  bf16* xp2 = (bf16*)alloc((size_t)16384 * 2048 * 2);

  prep<<<18561, 256, 0, stream>>>(
      conds, conds_b,
      operators, ops_b, extras, ext_b,
      (const float*)d_in[5], w1ih_b, (const float*)d_in[6], w1hh_b,
      (const float*)d_in[9], condw_b, (const float*)d_in[13], w2ih_b,
      (const float*)d_in[14], w2hh_b,
      mapping, flags);

  // -------- LSTM1: 8 fused K=768 GEMM+cell steps (BM=128 x BN=256) --------
  cell_gemm<4, 4, 0><<<dim3(128, 8), 256, 0, stream>>>(
      conds_b, 0, 2048, nullptr, 512,
      w1ih_b, 256, w1hh_b, 512,
      b1ih, b1hh, nullptr, c1, h1[1]);
  for (int t = 1; t < 8; ++t) {
    cell_gemm<4, 4, 8><<<dim3(128, 8), 256, 0, stream>>>(
        conds_b, t * 256, 2048, h1[t & 1], 512,
        w1ih_b, 256, w1hh_b, 512,
        b1ih, b1hh, c1, c1, h1[(t + 1) & 1]);
  }

  // -------- last = relu(h1 @ condW^T + condb); BN1 stats + weight fold ----
  plain_gemm<2><<<dim3(256, 2), 256, 0, stream>>>(
      h1[0], 512, 16, nullptr, 0, 0, nullptr, 0, 0,
      condw_b, 512, condb, 1, last_relu, 256);
  bn_reduce_b16<<<64, 256, 0, stream>>>(last_relu, 256, 256, partials);
  bn_final<<<1, 256, 0, stream>>>(partials, 64, 256, bn1g, bn1b, 1.f / 16384.f, scale1, shift1);
  fold_w2<<<256, 256, 0, stream>>>(w2ih_b, scale1, shift1, b2ih, w2ih_f, bias2f);

  // -------- xp2 = concat(ops, extras, BN1(last)) @ W2ih^T + b2ih ----------
  // BN folded into w2ih_f/bias2f; A2 = last_relu directly.
  plain_gemm<4><<<dim3(128, 16), 256, 0, stream>>>(
      ops_b, 32, 1, ext_b, 32, 1, last_relu, 256, 8,
      w2ih_f, 320, bias2f, 0, xp2, 2048);

  // -------- LSTM2 tree: fused gather+GEMM per level, h/c ping-pong --------
  size_t lvl_sz = (size_t)1024 * 2048;
  bf16* hb[2] = {hbuf0, hbuf1};
  float* cb[2] = {cbuf0, cbuf1};
  cell0<<<1024, 512, 0, stream>>>(xp2 + 15 * lvl_sz, b2hh, hb[0], cb[0]);
  int cur = 0;
  for (int idx = 14; idx >= 0; --idx) {
    int nxt = cur ^ 1;
    cell_tree_f<<<dim3(32, 16), 256, 0, stream>>>(
        mapping, flags, idx, hb[cur], cb[cur], w2hh_b, b2hh,
        xp2 + (size_t)idx * lvl_sz, cb[nxt], hb[nxt],
        (idx == 0) ? h2f : nullptr);
    cur = nxt;
  }

  // -------- BN2 -> output --------
  bn_reduce_f32<<<16, 512, 0, stream>>>(h2f, 64, 512, partials);
  bn_final<<<1, 512, 0, stream>>>(partials, 16, 512, bn2g, bn2b, 1.f / 1024.f, scale2, shift2);
  bn_apply_out<<<512, 256, 0, stream>>>(h2f, scale2, shift2, 511,
                                        (size_t)1024 * 512, (float*)d_out);
}